// Round 1
// baseline (1066.893 us; speedup 1.0000x reference)
//
#include <hip/hip_runtime.h>
#include <hip/hip_bf16.h>

#define N_NODES 50000
#define E_EDGES 800000

// ---------------- elementwise prep: h0 = x/1000 - 0.5 ----------------
__global__ void k_prep(const float* __restrict__ x, float* __restrict__ h0) {
    int total = N_NODES * 128;
    for (int i = blockIdx.x * blockDim.x + threadIdx.x; i < total;
         i += gridDim.x * blockDim.x)
        h0[i] = x[i] * 0.001f - 0.5f;
}

// ---------------- degree count ----------------
__global__ void k_count(const int* __restrict__ dst, int* __restrict__ deg) {
    for (int i = blockIdx.x * blockDim.x + threadIdx.x; i < E_EDGES;
         i += gridDim.x * blockDim.x)
        atomicAdd(&deg[dst[i]], 1);
}

// ---------------- exclusive scan of degrees -> rowptr, plus 1/max(deg,1) ----------------
__global__ __launch_bounds__(1024) void k_scan(const int* __restrict__ deg,
                                               int* __restrict__ rowptr,
                                               float* __restrict__ dinv) {
    __shared__ int partial[1024];
    const int tid = threadIdx.x;
    const int CH = (N_NODES + 1023) / 1024;  // 49
    int start = tid * CH;
    int sum = 0;
    for (int j = 0; j < CH; ++j) {
        int idx = start + j;
        if (idx < N_NODES) sum += deg[idx];
    }
    partial[tid] = sum;
    __syncthreads();
    for (int ofs = 1; ofs < 1024; ofs <<= 1) {
        int v = (tid >= ofs) ? partial[tid - ofs] : 0;
        __syncthreads();
        partial[tid] += v;
        __syncthreads();
    }
    int run = (tid == 0) ? 0 : partial[tid - 1];
    for (int j = 0; j < CH; ++j) {
        int idx = start + j;
        if (idx < N_NODES) {
            rowptr[idx] = run;
            int d = deg[idx];
            run += d;
            dinv[idx] = 1.0f / fmaxf((float)d, 1.0f);
        }
    }
    if (tid == 1023) rowptr[N_NODES] = run;
}

// ---------------- CSR fill ----------------
__global__ void k_fill(const int* __restrict__ src, const int* __restrict__ dst,
                       const int* __restrict__ rowptr, int* __restrict__ cursor,
                       int* __restrict__ colidx) {
    for (int i = blockIdx.x * blockDim.x + threadIdx.x; i < E_EDGES;
         i += gridDim.x * blockDim.x) {
        int d = dst[i];
        int pos = rowptr[d] + atomicAdd(&cursor[d], 1);
        colidx[pos] = src[i];
    }
}

// ---------------- neighbor-mean aggregation: one wave per node ----------------
template <int D>
__global__ __launch_bounds__(256) void k_aggregate(
    const float* __restrict__ h, const int* __restrict__ rowptr,
    const int* __restrict__ colidx, const float* __restrict__ dinv,
    float* __restrict__ mean) {
    constexpr int V = D / 64;  // floats per lane (2 or 4)
    int node = (int)((blockIdx.x * 256 + threadIdx.x) >> 6);
    int lane = threadIdx.x & 63;
    if (node >= N_NODES) return;
    int beg = rowptr[node], end = rowptr[node + 1];
    float acc[V] = {};
    for (int e = beg; e < end; ++e) {
        int s = colidx[e];
        const float* row = h + (size_t)s * D + lane * V;
        if (V == 2) {
            float2 r = *(const float2*)row;
            acc[0] += r.x;
            acc[1] += r.y;
        } else {
            float4 r = *(const float4*)row;
            acc[0] += r.x;
            acc[1] += r.y;
            acc[2] += r.z;
            acc[3] += r.w;
        }
    }
    float inv = dinv[node];
    float* o = mean + (size_t)node * D + lane * V;
    if (V == 2) {
        *(float2*)o = make_float2(acc[0] * inv, acc[1] * inv);
    } else {
        *(float4*)o = make_float4(acc[0] * inv, acc[1] * inv, acc[2] * inv,
                                  acc[3] * inv);
    }
}

// ---------------- fp32 GEMM: C = A1@W1 + A2@W2 + bias, with epilogue ----------------
// BM=64, BN=64, BK=16, 256 threads, 4x4 micro-tile per thread.
// A row-major MxK (both A share K), W row-major KxNc, C row-major MxNc.
enum { ACT_NONE = 0, ACT_SIN = 1, ACT_RELU = 2, ACT_SIGMOID1000 = 3 };

template <int ACT>
__global__ __launch_bounds__(256) void k_gemm(
    const float* __restrict__ A1, const float* __restrict__ W1,
    const float* __restrict__ A2, const float* __restrict__ W2,
    const float* __restrict__ bias, float* __restrict__ C, int M, int K,
    int Nc) {
    __shared__ float As[16][68];  // [k][m], padded to kill bank conflicts
    __shared__ float Ws[16][64];  // [k][n]
    const int t = threadIdx.x;
    const int m0 = blockIdx.x * 64;
    const int n0 = blockIdx.y * 64;
    const int tm = (t >> 4) * 4;   // 0..60
    const int tn = (t & 15) * 4;   // 0..60
    const int mA = t >> 4;         // 0..15
    const int kA = t & 15;         // 0..15
    const int nW = t & 63;         // 0..63
    const int kW = t >> 6;         // 0..3

    float acc[4][4] = {};

    for (int pass = 0; pass < 2; ++pass) {
        const float* A = pass ? A2 : A1;
        const float* W = pass ? W2 : W1;
        if (!A) break;
        for (int k0 = 0; k0 < K; k0 += 16) {
#pragma unroll
            for (int i = 0; i < 4; ++i) {
                int row = m0 + mA + 16 * i;
                As[kA][mA + 16 * i] =
                    (row < M) ? A[(size_t)row * K + k0 + kA] : 0.f;
            }
#pragma unroll
            for (int i = 0; i < 4; ++i) {
                Ws[kW + 4 * i][nW] = W[(size_t)(k0 + kW + 4 * i) * Nc + n0 + nW];
            }
            __syncthreads();
#pragma unroll
            for (int k = 0; k < 16; ++k) {
                float4 av = *(const float4*)&As[k][tm];
                float4 bv = *(const float4*)&Ws[k][tn];
                float a[4] = {av.x, av.y, av.z, av.w};
                float b[4] = {bv.x, bv.y, bv.z, bv.w};
#pragma unroll
                for (int i = 0; i < 4; ++i)
#pragma unroll
                    for (int j = 0; j < 4; ++j) acc[i][j] += a[i] * b[j];
            }
            __syncthreads();
        }
    }

#pragma unroll
    for (int i = 0; i < 4; ++i) {
        int row = m0 + tm + i;
        if (row >= M) continue;
#pragma unroll
        for (int j = 0; j < 4; ++j) {
            float v = acc[i][j] + bias[n0 + tn + j];
            if (ACT == ACT_SIN) v = __sinf(v);
            else if (ACT == ACT_RELU) v = fmaxf(v, 0.f);
            else if (ACT == ACT_SIGMOID1000) v = 1000.f / (1.f + __expf(-v));
            C[(size_t)row * Nc + n0 + tn + j] = v;
        }
    }
}

// ---------------- reparameterization + write mean/log_var outputs ----------------
__global__ void k_z(const float* __restrict__ h2, const float* __restrict__ eps,
                    float* __restrict__ out_mean, float* __restrict__ out_lv,
                    float* __restrict__ z) {
    int total = N_NODES * 128;
    for (int i = blockIdx.x * blockDim.x + threadIdx.x; i < total;
         i += gridDim.x * blockDim.x) {
        int node = i >> 7;
        int d = i & 127;
        float mv = h2[(size_t)node * 256 + d];
        float lv = h2[(size_t)node * 256 + 128 + d];
        out_mean[i] = mv;
        out_lv[i] = lv;
        z[i] = mv + __expf(lv) * eps[i];
    }
}

extern "C" void kernel_launch(void* const* d_in, const int* in_sizes, int n_in,
                              void* d_out, int out_size, void* d_ws,
                              size_t ws_size, hipStream_t stream) {
    const int N = N_NODES;
    const float* x = (const float*)d_in[0];
    const int* ei = (const int*)d_in[1];
    const float* eps = (const float*)d_in[2];
    const float* Wl1 = (const float*)d_in[3];
    const float* bl1 = (const float*)d_in[4];
    const float* Wr1 = (const float*)d_in[5];
    const float* Wl2 = (const float*)d_in[6];
    const float* bl2 = (const float*)d_in[7];
    const float* Wr2 = (const float*)d_in[8];
    const float* Wl3 = (const float*)d_in[9];
    const float* bl3 = (const float*)d_in[10];
    const float* Wr3 = (const float*)d_in[11];
    const float* Wl4 = (const float*)d_in[12];
    const float* bl4 = (const float*)d_in[13];
    const float* Wr4 = (const float*)d_in[14];
    const float* W_lin = (const float*)d_in[15];
    const float* b_lin = (const float*)d_in[16];

    const int* src = ei;
    const int* dst = ei + E_EDGES;

    char* w = (char*)d_ws;
    auto alloc = [&](size_t b) {
        void* p = (void*)w;
        w += (b + 255) & ~(size_t)255;
        return p;
    };
    int* deg = (int*)alloc((size_t)N * 4);
    int* rowptr = (int*)alloc((size_t)(N + 1) * 4);
    int* cursor = (int*)alloc((size_t)N * 4);
    int* colidx = (int*)alloc((size_t)E_EDGES * 4);
    float* dinv = (float*)alloc((size_t)N * 4);
    float* bufA = (float*)alloc((size_t)N * 256 * 4);
    float* bufB = (float*)alloc((size_t)N * 256 * 4);
    float* bufC = (float*)alloc((size_t)N * 256 * 4);

    float* out_final = (float*)d_out;                    // N x 64
    float* out_mean = out_final + (size_t)N * 64;        // N x 128
    float* out_lv = out_mean + (size_t)N * 128;          // N x 128

    hipMemsetAsync(deg, 0, (size_t)N * 4, stream);
    hipMemsetAsync(cursor, 0, (size_t)N * 4, stream);

    // h0 -> bufA
    k_prep<<<2048, 256, 0, stream>>>(x, bufA);
    k_count<<<3125, 256, 0, stream>>>(dst, deg);
    k_scan<<<1, 1024, 0, stream>>>(deg, rowptr, dinv);
    k_fill<<<3125, 256, 0, stream>>>(src, dst, rowptr, cursor, colidx);

    const int aggBlocks = (N * 64 + 255) / 256;  // one wave per node
    const int gm = (N + 63) / 64;                // 782

    // conv1: h1 = sin(mean(h0)@Wl1 + bl1 + h0@Wr1)   (N x 256) -> bufC
    k_aggregate<128><<<aggBlocks, 256, 0, stream>>>(bufA, rowptr, colidx, dinv,
                                                    bufB);
    k_gemm<ACT_SIN><<<dim3(gm, 4), 256, 0, stream>>>(bufB, Wl1, bufA, Wr1, bl1,
                                                     bufC, N, 128, 256);

    // conv2: h2 = mean(h1)@Wl2 + bl2 + h1@Wr2        (N x 256) -> bufA
    k_aggregate<256><<<aggBlocks, 256, 0, stream>>>(bufC, rowptr, colidx, dinv,
                                                    bufB);
    k_gemm<ACT_NONE><<<dim3(gm, 4), 256, 0, stream>>>(bufB, Wl2, bufC, Wr2, bl2,
                                                      bufA, N, 256, 256);

    // z = mean + exp(log_var)*eps; write mean/log_var outputs -> bufC (N x 128)
    k_z<<<2048, 256, 0, stream>>>(bufA, eps, out_mean, out_lv, bufC);

    // conv3: h3 = relu(mean(z)@Wl3 + bl3 + z@Wr3)    (N x 128) -> bufA
    k_aggregate<128><<<aggBlocks, 256, 0, stream>>>(bufC, rowptr, colidx, dinv,
                                                    bufB);
    k_gemm<ACT_RELU><<<dim3(gm, 2), 256, 0, stream>>>(bufB, Wl3, bufC, Wr3, bl3,
                                                      bufA, N, 128, 128);

    // conv4: h4 = relu(mean(h3)@Wl4 + bl4 + h3@Wr4)  (N x 128) -> bufC
    k_aggregate<128><<<aggBlocks, 256, 0, stream>>>(bufA, rowptr, colidx, dinv,
                                                    bufB);
    k_gemm<ACT_RELU><<<dim3(gm, 2), 256, 0, stream>>>(bufB, Wl4, bufA, Wr4, bl4,
                                                      bufC, N, 128, 128);

    // out = sigmoid(h4 @ W_lin + b_lin) * 1000       (N x 64) -> d_out
    k_gemm<ACT_SIGMOID1000><<<dim3(gm, 1), 256, 0, stream>>>(
        bufC, W_lin, nullptr, nullptr, b_lin, out_final, N, 128, 64);
}

// Round 2
// 756.608 us; speedup vs baseline: 1.4101x; 1.4101x over previous
//
#include <hip/hip_runtime.h>
#include <hip/hip_bf16.h>

#define N_NODES 50000
#define E_EDGES 800000

using u16 = unsigned short;
typedef short bf8 __attribute__((ext_vector_type(8)));
typedef float f32x4 __attribute__((ext_vector_type(4)));

__device__ __forceinline__ float bf2f(u16 h) {
    union { unsigned u; float f; } v;
    v.u = ((unsigned)h) << 16;
    return v.f;
}
__device__ __forceinline__ u16 f2bf(float f) {
    union { float f; unsigned u; } v;
    v.f = f;
    unsigned r = v.u + 0x7FFF + ((v.u >> 16) & 1);
    return (u16)(r >> 16);
}

// ---------------- weight transpose+cast: Wt[n][k] = bf16(W[k][n]) ----------------
struct WtArgs {
    const float* src[9];
    u16* dst[9];
    int K[9];
    int N[9];
};

__global__ __launch_bounds__(256) void k_wt(WtArgs a) {
    int wi = blockIdx.y;
    int K = a.K[wi], Nn = a.N[wi];
    int tot = K * Nn;
    for (int i = blockIdx.x * 256 + threadIdx.x; i < tot; i += gridDim.x * 256) {
        int n = i / K, k = i % K;
        a.dst[wi][i] = f2bf(a.src[wi][(size_t)k * Nn + n]);
    }
}

// ---------------- prep: h0 = x/1000 - 0.5, fp32 -> bf16 ----------------
__global__ __launch_bounds__(256) void k_prep(const float* __restrict__ x,
                                              u16* __restrict__ h0) {
    int total = N_NODES * 128 / 4;
    for (int i = blockIdx.x * 256 + threadIdx.x; i < total;
         i += gridDim.x * 256) {
        float4 v = *(const float4*)(x + (size_t)i * 4);
        ushort4 o;
        o.x = f2bf(v.x * 0.001f - 0.5f);
        o.y = f2bf(v.y * 0.001f - 0.5f);
        o.z = f2bf(v.z * 0.001f - 0.5f);
        o.w = f2bf(v.w * 0.001f - 0.5f);
        *(ushort4*)(h0 + (size_t)i * 4) = o;
    }
}

// ---------------- degree count ----------------
__global__ void k_count(const int* __restrict__ dst, int* __restrict__ deg) {
    for (int i = blockIdx.x * blockDim.x + threadIdx.x; i < E_EDGES;
         i += gridDim.x * blockDim.x)
        atomicAdd(&deg[dst[i]], 1);
}

// ---------------- exclusive scan -> rowptr + 1/max(deg,1) ----------------
__global__ __launch_bounds__(1024) void k_scan(const int* __restrict__ deg,
                                               int* __restrict__ rowptr,
                                               float* __restrict__ dinv) {
    __shared__ int partial[1024];
    const int tid = threadIdx.x;
    const int CH = (N_NODES + 1023) / 1024;
    int start = tid * CH;
    int sum = 0;
    for (int j = 0; j < CH; ++j) {
        int idx = start + j;
        if (idx < N_NODES) sum += deg[idx];
    }
    partial[tid] = sum;
    __syncthreads();
    for (int ofs = 1; ofs < 1024; ofs <<= 1) {
        int v = (tid >= ofs) ? partial[tid - ofs] : 0;
        __syncthreads();
        partial[tid] += v;
        __syncthreads();
    }
    int run = (tid == 0) ? 0 : partial[tid - 1];
    for (int j = 0; j < CH; ++j) {
        int idx = start + j;
        if (idx < N_NODES) {
            rowptr[idx] = run;
            int d = deg[idx];
            run += d;
            dinv[idx] = 1.0f / fmaxf((float)d, 1.0f);
        }
    }
    if (tid == 1023) rowptr[N_NODES] = run;
}

// ---------------- CSR fill ----------------
__global__ void k_fill(const int* __restrict__ src, const int* __restrict__ dst,
                       const int* __restrict__ rowptr, int* __restrict__ cursor,
                       int* __restrict__ colidx) {
    for (int i = blockIdx.x * blockDim.x + threadIdx.x; i < E_EDGES;
         i += gridDim.x * blockDim.x) {
        int d = dst[i];
        int pos = rowptr[d] + atomicAdd(&cursor[d], 1);
        colidx[pos] = src[i];
    }
}

// ---------------- neighbor-mean aggregation (bf16): one wave per node ----------------
template <int D>
__global__ __launch_bounds__(256) void k_aggregate(
    const u16* __restrict__ h, const int* __restrict__ rowptr,
    const int* __restrict__ colidx, const float* __restrict__ dinv,
    u16* __restrict__ mean) {
    constexpr int V = D / 64;  // bf16 per lane (2 or 4)
    int node = (int)((blockIdx.x * 256 + threadIdx.x) >> 6);
    int lane = threadIdx.x & 63;
    if (node >= N_NODES) return;
    int beg = rowptr[node], end = rowptr[node + 1];
    float acc[V] = {};
    for (int e = beg; e < end; ++e) {
        int s = colidx[e];
        const u16* row = h + (size_t)s * D + lane * V;
        if (V == 2) {
            ushort2 r = *(const ushort2*)row;
            acc[0] += bf2f(r.x);
            acc[1] += bf2f(r.y);
        } else {
            ushort4 r = *(const ushort4*)row;
            acc[0] += bf2f(r.x);
            acc[1] += bf2f(r.y);
            acc[2] += bf2f(r.z);
            acc[3] += bf2f(r.w);
        }
    }
    float inv = dinv[node];
    u16* o = mean + (size_t)node * D + lane * V;
    if (V == 2) {
        ushort2 r;
        r.x = f2bf(acc[0] * inv);
        r.y = f2bf(acc[1] * inv);
        *(ushort2*)o = r;
    } else {
        ushort4 r;
        r.x = f2bf(acc[0] * inv);
        r.y = f2bf(acc[1] * inv);
        r.z = f2bf(acc[2] * inv);
        r.w = f2bf(acc[3] * inv);
        *(ushort4*)o = r;
    }
}

// ---------------- bf16 MFMA GEMM: C = A1@W1 + A2@W2 + bias, epilogue ----------------
// BM=64, BN=64, 4 waves (2x2), each wave 32x32 via 2x2 mfma_f32_16x16x32_bf16.
// A row-major MxK bf16; Wt row-major [Nc][K] bf16 (pre-transposed weights).
enum { ACT_NONE = 0, ACT_SIN = 1, ACT_RELU = 2, ACT_SIGMOID1000 = 3 };

template <int ACT, bool OUT_F32>
__global__ __launch_bounds__(256) void k_gemm(
    const u16* __restrict__ A1, const u16* __restrict__ Wt1,
    const u16* __restrict__ A2, const u16* __restrict__ Wt2,
    const float* __restrict__ bias, void* __restrict__ Cout, int M, int K,
    int Nc) {
    extern __shared__ char smem[];
    const int pk = K + 8;  // padded row stride (elements)
    u16* As = (u16*)smem;
    u16* Bs = (u16*)(smem + (size_t)64 * pk * 2);

    const int t = threadIdx.x;
    const int lane = t & 63;
    const int w = t >> 6;
    const int wr = w >> 1, wc = w & 1;
    const int m0 = blockIdx.x * 64;
    const int n0 = blockIdx.y * 64;
    const int lr = lane & 15;
    const int lk = (lane >> 4) * 8;
    const int CR = K / 8;  // 16B chunks per row

    f32x4 acc[2][2];
#pragma unroll
    for (int i = 0; i < 2; ++i)
#pragma unroll
        for (int j = 0; j < 2; ++j) acc[i][j] = (f32x4){0.f, 0.f, 0.f, 0.f};

    for (int pass = 0; pass < 2; ++pass) {
        const u16* A = pass ? A2 : A1;
        const u16* Wt = pass ? Wt2 : Wt1;
        if (!A) break;
        // stage A tile (64 x K) and W-slice (64 x K) into LDS
        for (int c = t; c < 64 * CR; c += 256) {
            int row = c / CR, kc = c % CR;
            int gr = m0 + row;
            bf8 v = {0, 0, 0, 0, 0, 0, 0, 0};
            if (gr < M) v = *(const bf8*)(A + (size_t)gr * K + kc * 8);
            *(bf8*)&As[row * pk + kc * 8] = v;
        }
        for (int c = t; c < 64 * CR; c += 256) {
            int row = c / CR, kc = c % CR;
            *(bf8*)&Bs[row * pk + kc * 8] =
                *(const bf8*)(Wt + (size_t)(n0 + row) * K + kc * 8);
        }
        __syncthreads();
#pragma unroll 4
        for (int k0 = 0; k0 < K; k0 += 32) {
            bf8 a0 = *(const bf8*)&As[(wr * 32 + lr) * pk + k0 + lk];
            bf8 a1 = *(const bf8*)&As[(wr * 32 + 16 + lr) * pk + k0 + lk];
            bf8 b0 = *(const bf8*)&Bs[(wc * 32 + lr) * pk + k0 + lk];
            bf8 b1 = *(const bf8*)&Bs[(wc * 32 + 16 + lr) * pk + k0 + lk];
            acc[0][0] = __builtin_amdgcn_mfma_f32_16x16x32_bf16(a0, b0,
                                                                acc[0][0], 0, 0, 0);
            acc[0][1] = __builtin_amdgcn_mfma_f32_16x16x32_bf16(a0, b1,
                                                                acc[0][1], 0, 0, 0);
            acc[1][0] = __builtin_amdgcn_mfma_f32_16x16x32_bf16(a1, b0,
                                                                acc[1][0], 0, 0, 0);
            acc[1][1] = __builtin_amdgcn_mfma_f32_16x16x32_bf16(a1, b1,
                                                                acc[1][1], 0, 0, 0);
        }
        __syncthreads();
    }

    // epilogue: C[row][col], row = m0+wr*32+mi*16+(lane>>4)*4+r, col = n0+wc*32+ni*16+lr
#pragma unroll
    for (int ni = 0; ni < 2; ++ni) {
        int col = n0 + wc * 32 + ni * 16 + lr;
        float bv = bias[col];
#pragma unroll
        for (int mi = 0; mi < 2; ++mi) {
#pragma unroll
            for (int r = 0; r < 4; ++r) {
                int row = m0 + wr * 32 + mi * 16 + (lane >> 4) * 4 + r;
                if (row >= M) continue;
                float v = acc[mi][ni][r] + bv;
                if (ACT == ACT_SIN) v = __sinf(v);
                else if (ACT == ACT_RELU) v = fmaxf(v, 0.f);
                else if (ACT == ACT_SIGMOID1000) v = 1000.f / (1.f + __expf(-v));
                if (OUT_F32)
                    ((float*)Cout)[(size_t)row * Nc + col] = v;
                else
                    ((u16*)Cout)[(size_t)row * Nc + col] = f2bf(v);
            }
        }
    }
}

// ---------------- reparameterization + mean/log_var outputs ----------------
__global__ __launch_bounds__(256) void k_z(const float* __restrict__ h2,
                                           const float* __restrict__ eps,
                                           float* __restrict__ out_mean,
                                           float* __restrict__ out_lv,
                                           u16* __restrict__ z) {
    int total = N_NODES * 128;
    for (int i = blockIdx.x * 256 + threadIdx.x; i < total;
         i += gridDim.x * 256) {
        int node = i >> 7;
        int d = i & 127;
        float mv = h2[(size_t)node * 256 + d];
        float lv = h2[(size_t)node * 256 + 128 + d];
        out_mean[i] = mv;
        out_lv[i] = lv;
        z[i] = f2bf(mv + __expf(lv) * eps[i]);
    }
}

extern "C" void kernel_launch(void* const* d_in, const int* in_sizes, int n_in,
                              void* d_out, int out_size, void* d_ws,
                              size_t ws_size, hipStream_t stream) {
    const int N = N_NODES;
    const float* x = (const float*)d_in[0];
    const int* ei = (const int*)d_in[1];
    const float* eps = (const float*)d_in[2];
    const float* Wl1 = (const float*)d_in[3];
    const float* bl1 = (const float*)d_in[4];
    const float* Wr1 = (const float*)d_in[5];
    const float* Wl2 = (const float*)d_in[6];
    const float* bl2 = (const float*)d_in[7];
    const float* Wr2 = (const float*)d_in[8];
    const float* Wl3 = (const float*)d_in[9];
    const float* bl3 = (const float*)d_in[10];
    const float* Wr3 = (const float*)d_in[11];
    const float* Wl4 = (const float*)d_in[12];
    const float* bl4 = (const float*)d_in[13];
    const float* Wr4 = (const float*)d_in[14];
    const float* W_lin = (const float*)d_in[15];
    const float* b_lin = (const float*)d_in[16];

    const int* src = ei;
    const int* dst = ei + E_EDGES;

    char* w = (char*)d_ws;
    auto alloc = [&](size_t b) {
        void* p = (void*)w;
        w += (b + 255) & ~(size_t)255;
        return p;
    };
    int* deg = (int*)alloc((size_t)N * 4);
    int* rowptr = (int*)alloc((size_t)(N + 1) * 4);
    int* cursor = (int*)alloc((size_t)N * 4);
    int* colidx = (int*)alloc((size_t)E_EDGES * 4);
    float* dinv = (float*)alloc((size_t)N * 4);
    u16* hbA = (u16*)alloc((size_t)N * 256 * 2);   // bf16 activations
    u16* hbB = (u16*)alloc((size_t)N * 256 * 2);   // aggregation output
    u16* hbC = (u16*)alloc((size_t)N * 256 * 2);
    float* h2f = (float*)alloc((size_t)N * 256 * 4);  // conv2 out (fp32)
    // transposed bf16 weights: Wl1,Wr1,Wl2,Wr2,Wl3,Wr3,Wl4,Wr4,W_lin
    static const int wK[9] = {128, 128, 256, 256, 128, 128, 128, 128, 128};
    static const int wN[9] = {256, 256, 256, 256, 128, 128, 128, 128, 64};
    u16* Wt[9];
    for (int i = 0; i < 9; ++i) Wt[i] = (u16*)alloc((size_t)wK[i] * wN[i] * 2);

    float* out_final = (float*)d_out;              // N x 64
    float* out_mean = out_final + (size_t)N * 64;  // N x 128
    float* out_lv = out_mean + (size_t)N * 128;    // N x 128

    hipMemsetAsync(deg, 0, (size_t)N * 4, stream);
    hipMemsetAsync(cursor, 0, (size_t)N * 4, stream);

    // transpose+cast all weights
    WtArgs wa;
    const float* wsrc[9] = {Wl1, Wr1, Wl2, Wr2, Wl3, Wr3, Wl4, Wr4, W_lin};
    for (int i = 0; i < 9; ++i) {
        wa.src[i] = wsrc[i];
        wa.dst[i] = Wt[i];
        wa.K[i] = wK[i];
        wa.N[i] = wN[i];
    }
    k_wt<<<dim3(64, 9), 256, 0, stream>>>(wa);

    k_prep<<<2048, 256, 0, stream>>>(x, hbA);
    k_count<<<3125, 256, 0, stream>>>(dst, deg);
    k_scan<<<1, 1024, 0, stream>>>(deg, rowptr, dinv);
    k_fill<<<3125, 256, 0, stream>>>(src, dst, rowptr, cursor, colidx);

    const int aggBlocks = (N * 64 + 255) / 256;  // one wave per node
    const int gm = (N + 63) / 64;                // 782
    auto shm = [](int K) { return (size_t)2 * 64 * (K + 8) * 2; };

    // conv1: h1 = sin(mean(h0)@Wl1 + bl1 + h0@Wr1)  (N x 256) -> hbC
    k_aggregate<128><<<aggBlocks, 256, 0, stream>>>(hbA, rowptr, colidx, dinv,
                                                    hbB);
    k_gemm<ACT_SIN, false><<<dim3(gm, 4), 256, shm(128), stream>>>(
        hbB, Wt[0], hbA, Wt[1], bl1, hbC, N, 128, 256);

    // conv2: h2 = mean(h1)@Wl2 + bl2 + h1@Wr2       (N x 256, fp32) -> h2f
    k_aggregate<256><<<aggBlocks, 256, 0, stream>>>(hbC, rowptr, colidx, dinv,
                                                    hbB);
    k_gemm<ACT_NONE, true><<<dim3(gm, 4), 256, shm(256), stream>>>(
        hbB, Wt[2], hbC, Wt[3], bl2, h2f, N, 256, 256);

    // z = mean + exp(log_var)*eps -> hbA (bf16 N x 128); write outputs
    k_z<<<2048, 256, 0, stream>>>(h2f, eps, out_mean, out_lv, hbA);

    // conv3: h3 = relu(mean(z)@Wl3 + bl3 + z@Wr3)   (N x 128) -> hbC
    k_aggregate<128><<<aggBlocks, 256, 0, stream>>>(hbA, rowptr, colidx, dinv,
                                                    hbB);
    k_gemm<ACT_RELU, false><<<dim3(gm, 2), 256, shm(128), stream>>>(
        hbB, Wt[4], hbA, Wt[5], bl3, hbC, N, 128, 128);

    // conv4: h4 = relu(mean(h3)@Wl4 + bl4 + h3@Wr4) (N x 128) -> hbA
    k_aggregate<128><<<aggBlocks, 256, 0, stream>>>(hbC, rowptr, colidx, dinv,
                                                    hbB);
    k_gemm<ACT_RELU, false><<<dim3(gm, 2), 256, shm(128), stream>>>(
        hbB, Wt[6], hbC, Wt[7], bl4, hbA, N, 128, 128);

    // out = sigmoid(h4 @ W_lin + b_lin) * 1000      (N x 64) -> d_out
    k_gemm<ACT_SIGMOID1000, true><<<dim3(gm, 1), 256, shm(128), stream>>>(
        hbA, Wt[8], nullptr, nullptr, b_lin, out_final, N, 128, 64);
}

// Round 3
// 491.015 us; speedup vs baseline: 2.1728x; 1.5409x over previous
//
#include <hip/hip_runtime.h>
#include <hip/hip_bf16.h>

#define N_NODES 50000
#define E_EDGES 800000

using u16 = unsigned short;
typedef short bf8 __attribute__((ext_vector_type(8)));
typedef float f32x4 __attribute__((ext_vector_type(4)));

__device__ __forceinline__ float bf2f(u16 h) {
    union { unsigned u; float f; } v;
    v.u = ((unsigned)h) << 16;
    return v.f;
}
__device__ __forceinline__ u16 f2bf(float f) {
    union { float f; unsigned u; } v;
    v.f = f;
    unsigned r = v.u + 0x7FFF + ((v.u >> 16) & 1);
    return (u16)(r >> 16);
}

// ---------------- weight transpose+cast: Wt[n][k] = bf16(W[k][n]) ----------------
struct WtArgs {
    const float* src[9];
    u16* dst[9];
    int K[9];
    int N[9];
};

__global__ __launch_bounds__(256) void k_wt(WtArgs a) {
    int wi = blockIdx.y;
    int K = a.K[wi], Nn = a.N[wi];
    int tot = K * Nn;
    for (int i = blockIdx.x * 256 + threadIdx.x; i < tot; i += gridDim.x * 256) {
        int n = i / K, k = i % K;
        a.dst[wi][i] = f2bf(a.src[wi][(size_t)k * Nn + n]);
    }
}

// ---------------- prep: h0 = x/1000 - 0.5, fp32 -> bf16 ----------------
__global__ __launch_bounds__(256) void k_prep(const float* __restrict__ x,
                                              u16* __restrict__ h0) {
    int total = N_NODES * 128 / 4;
    for (int i = blockIdx.x * 256 + threadIdx.x; i < total;
         i += gridDim.x * 256) {
        float4 v = *(const float4*)(x + (size_t)i * 4);
        ushort4 o;
        o.x = f2bf(v.x * 0.001f - 0.5f);
        o.y = f2bf(v.y * 0.001f - 0.5f);
        o.z = f2bf(v.z * 0.001f - 0.5f);
        o.w = f2bf(v.w * 0.001f - 0.5f);
        *(ushort4*)(h0 + (size_t)i * 4) = o;
    }
}

// ---------------- degree count ----------------
__global__ void k_count(const int* __restrict__ dst, int* __restrict__ deg) {
    for (int i = blockIdx.x * blockDim.x + threadIdx.x; i < E_EDGES;
         i += gridDim.x * blockDim.x)
        atomicAdd(&deg[dst[i]], 1);
}

// ---------------- 3-phase parallel exclusive scan ----------------
#define SCAN_B 49  // ceil(50000/1024)

__global__ __launch_bounds__(1024) void k_scan1(const int* __restrict__ deg,
                                                int* __restrict__ bsum) {
    __shared__ int sm[1024];
    int i = blockIdx.x * 1024 + threadIdx.x;
    sm[threadIdx.x] = (i < N_NODES) ? deg[i] : 0;
    __syncthreads();
    for (int ofs = 512; ofs > 0; ofs >>= 1) {
        if (threadIdx.x < ofs) sm[threadIdx.x] += sm[threadIdx.x + ofs];
        __syncthreads();
    }
    if (threadIdx.x == 0) bsum[blockIdx.x] = sm[0];
}

__global__ void k_scan2(const int* __restrict__ bsum, int* __restrict__ bofs) {
    int l = threadIdx.x;  // one wave of 64
    int v = (l < SCAN_B) ? bsum[l] : 0;
    int orig = v;
    for (int d = 1; d < 64; d <<= 1) {
        int u = __shfl_up(v, d, 64);
        if (l >= d) v += u;
    }
    if (l < SCAN_B) bofs[l] = v - orig;  // exclusive
}

__global__ __launch_bounds__(1024) void k_scan3(const int* __restrict__ deg,
                                                const int* __restrict__ bofs,
                                                int* __restrict__ rowptr,
                                                float* __restrict__ dinv) {
    __shared__ int sm[1024];
    int i = blockIdx.x * 1024 + threadIdx.x;
    int d = (i < N_NODES) ? deg[i] : 0;
    sm[threadIdx.x] = d;
    __syncthreads();
    for (int ofs = 1; ofs < 1024; ofs <<= 1) {
        int u = (threadIdx.x >= (unsigned)ofs) ? sm[threadIdx.x - ofs] : 0;
        __syncthreads();
        sm[threadIdx.x] += u;
        __syncthreads();
    }
    if (i < N_NODES) {
        int incl = sm[threadIdx.x] + bofs[blockIdx.x];
        rowptr[i] = incl - d;
        dinv[i] = 1.0f / fmaxf((float)d, 1.0f);
        if (i == N_NODES - 1) rowptr[N_NODES] = incl;
    }
}

// ---------------- CSR fill ----------------
__global__ void k_fill(const int* __restrict__ src, const int* __restrict__ dst,
                       const int* __restrict__ rowptr, int* __restrict__ cursor,
                       int* __restrict__ colidx) {
    for (int i = blockIdx.x * blockDim.x + threadIdx.x; i < E_EDGES;
         i += gridDim.x * blockDim.x) {
        int d = dst[i];
        int pos = rowptr[d] + atomicAdd(&cursor[d], 1);
        colidx[pos] = src[i];
    }
}

// ---------------- neighbor-mean aggregation: 1 wave/node, 16 lanes/edge ----------------
template <int D>
__global__ __launch_bounds__(256) void k_aggregate(
    const u16* __restrict__ h, const int* __restrict__ rowptr,
    const int* __restrict__ colidx, const float* __restrict__ dinv,
    u16* __restrict__ mean) {
    constexpr int VA = D / 16;  // floats per lane (8 or 16)
    int node = (int)((blockIdx.x * 256 + threadIdx.x) >> 6);
    int lane = threadIdx.x & 63;
    if (node >= N_NODES) return;
    int sub = lane >> 4, lr = lane & 15;
    int beg = rowptr[node], end = rowptr[node + 1];
    float acc[VA] = {};
    for (int e = beg + sub; e < end; e += 4) {
        int s = colidx[e];
        const u16* row = h + (size_t)s * D + lr * VA;
        bf8 r0 = *(const bf8*)row;
#pragma unroll
        for (int j = 0; j < 8; ++j) acc[j] += bf2f((u16)r0[j]);
        if (VA == 16) {
            bf8 r1 = *(const bf8*)(row + 8);
#pragma unroll
            for (int j = 0; j < 8; ++j) acc[8 + j] += bf2f((u16)r1[j]);
        }
    }
#pragma unroll
    for (int j = 0; j < VA; ++j) {
        acc[j] += __shfl_xor(acc[j], 16);
        acc[j] += __shfl_xor(acc[j], 32);
    }
    if (sub == 0) {
        float inv = dinv[node];
        u16 outv[VA];
#pragma unroll
        for (int j = 0; j < VA; ++j) outv[j] = f2bf(acc[j] * inv);
        u16* o = mean + (size_t)node * D + lr * VA;
        *(bf8*)o = *(bf8*)&outv[0];
        if (VA == 16) *(bf8*)(o + 8) = *(bf8*)&outv[8];
    }
}

// ---------------- bf16 MFMA GEMM: C = A1@W1 + A2@W2 + bias, epilogue ----------------
enum { ACT_NONE = 0, ACT_SIN = 1, ACT_RELU = 2, ACT_SIGMOID1000 = 3 };

template <int ACT, bool OUT_F32>
__global__ __launch_bounds__(256) void k_gemm(
    const u16* __restrict__ A1, const u16* __restrict__ Wt1,
    const u16* __restrict__ A2, const u16* __restrict__ Wt2,
    const float* __restrict__ bias, void* __restrict__ Cout, int M, int K,
    int Nc) {
    extern __shared__ char smem[];
    const int pk = K + 8;  // padded row stride (elements)
    u16* As = (u16*)smem;
    u16* Bs = (u16*)(smem + (size_t)64 * pk * 2);

    const int t = threadIdx.x;
    const int lane = t & 63;
    const int w = t >> 6;
    const int wr = w >> 1, wc = w & 1;
    const int m0 = blockIdx.x * 64;
    const int n0 = blockIdx.y * 64;
    const int lr = lane & 15;
    const int lk = (lane >> 4) * 8;
    const int CR = K / 8;  // 16B chunks per row

    f32x4 acc[2][2];
#pragma unroll
    for (int i = 0; i < 2; ++i)
#pragma unroll
        for (int j = 0; j < 2; ++j) acc[i][j] = (f32x4){0.f, 0.f, 0.f, 0.f};

    for (int pass = 0; pass < 2; ++pass) {
        const u16* A = pass ? A2 : A1;
        const u16* Wt = pass ? Wt2 : Wt1;
        if (!A) break;
        for (int c = t; c < 64 * CR; c += 256) {
            int row = c / CR, kc = c % CR;
            int gr = m0 + row;
            bf8 v = {0, 0, 0, 0, 0, 0, 0, 0};
            if (gr < M) v = *(const bf8*)(A + (size_t)gr * K + kc * 8);
            *(bf8*)&As[row * pk + kc * 8] = v;
        }
        for (int c = t; c < 64 * CR; c += 256) {
            int row = c / CR, kc = c % CR;
            *(bf8*)&Bs[row * pk + kc * 8] =
                *(const bf8*)(Wt + (size_t)(n0 + row) * K + kc * 8);
        }
        __syncthreads();
#pragma unroll 4
        for (int k0 = 0; k0 < K; k0 += 32) {
            bf8 a0 = *(const bf8*)&As[(wr * 32 + lr) * pk + k0 + lk];
            bf8 a1 = *(const bf8*)&As[(wr * 32 + 16 + lr) * pk + k0 + lk];
            bf8 b0 = *(const bf8*)&Bs[(wc * 32 + lr) * pk + k0 + lk];
            bf8 b1 = *(const bf8*)&Bs[(wc * 32 + 16 + lr) * pk + k0 + lk];
            acc[0][0] = __builtin_amdgcn_mfma_f32_16x16x32_bf16(a0, b0,
                                                                acc[0][0], 0, 0, 0);
            acc[0][1] = __builtin_amdgcn_mfma_f32_16x16x32_bf16(a0, b1,
                                                                acc[0][1], 0, 0, 0);
            acc[1][0] = __builtin_amdgcn_mfma_f32_16x16x32_bf16(a1, b0,
                                                                acc[1][0], 0, 0, 0);
            acc[1][1] = __builtin_amdgcn_mfma_f32_16x16x32_bf16(a1, b1,
                                                                acc[1][1], 0, 0, 0);
        }
        __syncthreads();
    }

#pragma unroll
    for (int ni = 0; ni < 2; ++ni) {
        int col = n0 + wc * 32 + ni * 16 + lr;
        float bv = bias[col];
#pragma unroll
        for (int mi = 0; mi < 2; ++mi) {
#pragma unroll
            for (int r = 0; r < 4; ++r) {
                int row = m0 + wr * 32 + mi * 16 + (lane >> 4) * 4 + r;
                if (row >= M) continue;
                float v = acc[mi][ni][r] + bv;
                if (ACT == ACT_SIN) v = __sinf(v);
                else if (ACT == ACT_RELU) v = fmaxf(v, 0.f);
                else if (ACT == ACT_SIGMOID1000) v = 1000.f / (1.f + __expf(-v));
                if (OUT_F32)
                    ((float*)Cout)[(size_t)row * Nc + col] = v;
                else
                    ((u16*)Cout)[(size_t)row * Nc + col] = f2bf(v);
            }
        }
    }
}

// ---------------- reparameterization + mean/log_var outputs ----------------
__global__ __launch_bounds__(256) void k_z(const float* __restrict__ h2,
                                           const float* __restrict__ eps,
                                           float* __restrict__ out_mean,
                                           float* __restrict__ out_lv,
                                           u16* __restrict__ z) {
    int total = N_NODES * 128;
    for (int i = blockIdx.x * 256 + threadIdx.x; i < total;
         i += gridDim.x * 256) {
        int node = i >> 7;
        int d = i & 127;
        float mv = h2[(size_t)node * 256 + d];
        float lv = h2[(size_t)node * 256 + 128 + d];
        out_mean[i] = mv;
        out_lv[i] = lv;
        z[i] = f2bf(mv + __expf(lv) * eps[i]);
    }
}

extern "C" void kernel_launch(void* const* d_in, const int* in_sizes, int n_in,
                              void* d_out, int out_size, void* d_ws,
                              size_t ws_size, hipStream_t stream) {
    const int N = N_NODES;
    const float* x = (const float*)d_in[0];
    const int* ei = (const int*)d_in[1];
    const float* eps = (const float*)d_in[2];
    const float* Wl1 = (const float*)d_in[3];
    const float* bl1 = (const float*)d_in[4];
    const float* Wr1 = (const float*)d_in[5];
    const float* Wl2 = (const float*)d_in[6];
    const float* bl2 = (const float*)d_in[7];
    const float* Wr2 = (const float*)d_in[8];
    const float* Wl3 = (const float*)d_in[9];
    const float* bl3 = (const float*)d_in[10];
    const float* Wr3 = (const float*)d_in[11];
    const float* Wl4 = (const float*)d_in[12];
    const float* bl4 = (const float*)d_in[13];
    const float* Wr4 = (const float*)d_in[14];
    const float* W_lin = (const float*)d_in[15];
    const float* b_lin = (const float*)d_in[16];

    const int* src = ei;
    const int* dst = ei + E_EDGES;

    char* w = (char*)d_ws;
    auto alloc = [&](size_t b) {
        void* p = (void*)w;
        w += (b + 255) & ~(size_t)255;
        return p;
    };
    int* deg = (int*)alloc((size_t)N * 4);
    int* rowptr = (int*)alloc((size_t)(N + 1) * 4);
    int* cursor = (int*)alloc((size_t)N * 4);
    int* colidx = (int*)alloc((size_t)E_EDGES * 4);
    float* dinv = (float*)alloc((size_t)N * 4);
    int* bsum = (int*)alloc(64 * 4);
    int* bofs = (int*)alloc(64 * 4);
    u16* hbA = (u16*)alloc((size_t)N * 256 * 2);
    u16* hbB = (u16*)alloc((size_t)N * 256 * 2);
    u16* hbC = (u16*)alloc((size_t)N * 256 * 2);
    float* h2f = (float*)alloc((size_t)N * 256 * 4);
    static const int wK[9] = {128, 128, 256, 256, 128, 128, 128, 128, 128};
    static const int wN[9] = {256, 256, 256, 256, 128, 128, 128, 128, 64};
    u16* Wt[9];
    for (int i = 0; i < 9; ++i) Wt[i] = (u16*)alloc((size_t)wK[i] * wN[i] * 2);

    float* out_final = (float*)d_out;              // N x 64
    float* out_mean = out_final + (size_t)N * 64;  // N x 128
    float* out_lv = out_mean + (size_t)N * 128;    // N x 128

    hipMemsetAsync(deg, 0, (size_t)N * 4, stream);
    hipMemsetAsync(cursor, 0, (size_t)N * 4, stream);

    WtArgs wa;
    const float* wsrc[9] = {Wl1, Wr1, Wl2, Wr2, Wl3, Wr3, Wl4, Wr4, W_lin};
    for (int i = 0; i < 9; ++i) {
        wa.src[i] = wsrc[i];
        wa.dst[i] = Wt[i];
        wa.K[i] = wK[i];
        wa.N[i] = wN[i];
    }
    k_wt<<<dim3(64, 9), 256, 0, stream>>>(wa);

    k_prep<<<2048, 256, 0, stream>>>(x, hbA);
    k_count<<<3125, 256, 0, stream>>>(dst, deg);
    k_scan1<<<SCAN_B, 1024, 0, stream>>>(deg, bsum);
    k_scan2<<<1, 64, 0, stream>>>(bsum, bofs);
    k_scan3<<<SCAN_B, 1024, 0, stream>>>(deg, bofs, rowptr, dinv);
    k_fill<<<3125, 256, 0, stream>>>(src, dst, rowptr, cursor, colidx);

    const int aggBlocks = (N * 64 + 255) / 256;  // one wave per node
    const int gm = (N + 63) / 64;                // 782
    auto shm = [](int K) { return (size_t)2 * 64 * (K + 8) * 2; };

    // conv1: h1 = sin(mean(h0)@Wl1 + bl1 + h0@Wr1)  (N x 256) -> hbC
    k_aggregate<128><<<aggBlocks, 256, 0, stream>>>(hbA, rowptr, colidx, dinv,
                                                    hbB);
    k_gemm<ACT_SIN, false><<<dim3(gm, 4), 256, shm(128), stream>>>(
        hbB, Wt[0], hbA, Wt[1], bl1, hbC, N, 128, 256);

    // conv2: h2 = mean(h1)@Wl2 + bl2 + h1@Wr2       (N x 256, fp32) -> h2f
    k_aggregate<256><<<aggBlocks, 256, 0, stream>>>(hbC, rowptr, colidx, dinv,
                                                    hbB);
    k_gemm<ACT_NONE, true><<<dim3(gm, 4), 256, shm(256), stream>>>(
        hbB, Wt[2], hbC, Wt[3], bl2, h2f, N, 256, 256);

    // z = mean + exp(log_var)*eps -> hbA (bf16 N x 128); write outputs
    k_z<<<2048, 256, 0, stream>>>(h2f, eps, out_mean, out_lv, hbA);

    // conv3: h3 = relu(mean(z)@Wl3 + bl3 + z@Wr3)   (N x 128) -> hbC
    k_aggregate<128><<<aggBlocks, 256, 0, stream>>>(hbA, rowptr, colidx, dinv,
                                                    hbB);
    k_gemm<ACT_RELU, false><<<dim3(gm, 2), 256, shm(128), stream>>>(
        hbB, Wt[4], hbA, Wt[5], bl3, hbC, N, 128, 128);

    // conv4: h4 = relu(mean(h3)@Wl4 + bl4 + h3@Wr4) (N x 128) -> hbA
    k_aggregate<128><<<aggBlocks, 256, 0, stream>>>(hbC, rowptr, colidx, dinv,
                                                    hbB);
    k_gemm<ACT_RELU, false><<<dim3(gm, 2), 256, shm(128), stream>>>(
        hbB, Wt[6], hbC, Wt[7], bl4, hbA, N, 128, 128);

    // out = sigmoid(h4 @ W_lin + b_lin) * 1000      (N x 64) -> d_out
    k_gemm<ACT_SIGMOID1000, true><<<dim3(gm, 1), 256, shm(128), stream>>>(
        hbA, Wt[8], nullptr, nullptr, b_lin, out_final, N, 128, 64);
}

// Round 4
// 390.565 us; speedup vs baseline: 2.7317x; 1.2572x over previous
//
#include <hip/hip_runtime.h>
#include <hip/hip_bf16.h>

#define N_NODES 50000
#define E_EDGES 800000

using u16 = unsigned short;
typedef short bf8 __attribute__((ext_vector_type(8)));
typedef float f32x4 __attribute__((ext_vector_type(4)));

__device__ __forceinline__ float bf2f(u16 h) {
    union { unsigned u; float f; } v;
    v.u = ((unsigned)h) << 16;
    return v.f;
}
__device__ __forceinline__ u16 f2bf(float f) {
    union { float f; unsigned u; } v;
    v.f = f;
    unsigned r = v.u + 0x7FFF + ((v.u >> 16) & 1);
    return (u16)(r >> 16);
}

// ---------------- weight transpose+cast: Wt[n][k] = bf16(W[k][n]) ----------------
struct WtArgs {
    const float* src[9];
    u16* dst[9];
    int K[9];
    int N[9];
};

__global__ __launch_bounds__(256) void k_wt(WtArgs a) {
    int wi = blockIdx.y;
    int K = a.K[wi], Nn = a.N[wi];
    int tot = K * Nn;
    for (int i = blockIdx.x * 256 + threadIdx.x; i < tot; i += gridDim.x * 256) {
        int n = i / K, k = i % K;
        a.dst[wi][i] = f2bf(a.src[wi][(size_t)k * Nn + n]);
    }
}

// ---------------- prep: h0 = x/1000 - 0.5, fp32 -> bf16 ----------------
__global__ __launch_bounds__(256) void k_prep(const float* __restrict__ x,
                                              u16* __restrict__ h0) {
    int total = N_NODES * 128 / 4;
    for (int i = blockIdx.x * 256 + threadIdx.x; i < total;
         i += gridDim.x * 256) {
        float4 v = *(const float4*)(x + (size_t)i * 4);
        ushort4 o;
        o.x = f2bf(v.x * 0.001f - 0.5f);
        o.y = f2bf(v.y * 0.001f - 0.5f);
        o.z = f2bf(v.z * 0.001f - 0.5f);
        o.w = f2bf(v.w * 0.001f - 0.5f);
        *(ushort4*)(h0 + (size_t)i * 4) = o;
    }
}

// ---------------- degree count ----------------
__global__ void k_count(const int* __restrict__ dst, int* __restrict__ deg) {
    for (int i = blockIdx.x * blockDim.x + threadIdx.x; i < E_EDGES;
         i += gridDim.x * blockDim.x)
        atomicAdd(&deg[dst[i]], 1);
}

// ---------------- 3-phase parallel exclusive scan ----------------
#define SCAN_B 49  // ceil(50000/1024)

__global__ __launch_bounds__(1024) void k_scan1(const int* __restrict__ deg,
                                                int* __restrict__ bsum) {
    __shared__ int sm[1024];
    int i = blockIdx.x * 1024 + threadIdx.x;
    sm[threadIdx.x] = (i < N_NODES) ? deg[i] : 0;
    __syncthreads();
    for (int ofs = 512; ofs > 0; ofs >>= 1) {
        if (threadIdx.x < ofs) sm[threadIdx.x] += sm[threadIdx.x + ofs];
        __syncthreads();
    }
    if (threadIdx.x == 0) bsum[blockIdx.x] = sm[0];
}

__global__ void k_scan2(const int* __restrict__ bsum, int* __restrict__ bofs) {
    int l = threadIdx.x;  // one wave of 64
    int v = (l < SCAN_B) ? bsum[l] : 0;
    int orig = v;
    for (int d = 1; d < 64; d <<= 1) {
        int u = __shfl_up(v, d, 64);
        if (l >= d) v += u;
    }
    if (l < SCAN_B) bofs[l] = v - orig;  // exclusive
}

__global__ __launch_bounds__(1024) void k_scan3(const int* __restrict__ deg,
                                                const int* __restrict__ bofs,
                                                int* __restrict__ rowptr,
                                                float* __restrict__ dinv) {
    __shared__ int sm[1024];
    int i = blockIdx.x * 1024 + threadIdx.x;
    int d = (i < N_NODES) ? deg[i] : 0;
    sm[threadIdx.x] = d;
    __syncthreads();
    for (int ofs = 1; ofs < 1024; ofs <<= 1) {
        int u = (threadIdx.x >= (unsigned)ofs) ? sm[threadIdx.x - ofs] : 0;
        __syncthreads();
        sm[threadIdx.x] += u;
        __syncthreads();
    }
    if (i < N_NODES) {
        int incl = sm[threadIdx.x] + bofs[blockIdx.x];
        rowptr[i] = incl - d;
        dinv[i] = 1.0f / fmaxf((float)d, 1.0f);
        if (i == N_NODES - 1) rowptr[N_NODES] = incl;
    }
}

// ---------------- CSR fill ----------------
__global__ void k_fill(const int* __restrict__ src, const int* __restrict__ dst,
                       const int* __restrict__ rowptr, int* __restrict__ cursor,
                       int* __restrict__ colidx) {
    for (int i = blockIdx.x * blockDim.x + threadIdx.x; i < E_EDGES;
         i += gridDim.x * blockDim.x) {
        int d = dst[i];
        int pos = rowptr[d] + atomicAdd(&cursor[d], 1);
        colidx[pos] = src[i];
    }
}

// ---------------- neighbor-mean aggregation: 1 wave/node, 16 lanes/edge ----------------
template <int D>
__global__ __launch_bounds__(256) void k_aggregate(
    const u16* __restrict__ h, const int* __restrict__ rowptr,
    const int* __restrict__ colidx, const float* __restrict__ dinv,
    u16* __restrict__ mean) {
    constexpr int VA = D / 16;  // bf16 per lane (8 or 16)
    int node = (int)((blockIdx.x * 256 + threadIdx.x) >> 6);
    int lane = threadIdx.x & 63;
    if (node >= N_NODES) return;
    int sub = lane >> 4, lr = lane & 15;
    int beg = rowptr[node], end = rowptr[node + 1];
    float acc[VA] = {};
    for (int e = beg + sub; e < end; e += 4) {
        int s = colidx[e];
        const u16* row = h + (size_t)s * D + lr * VA;
        bf8 r0 = *(const bf8*)row;
#pragma unroll
        for (int j = 0; j < 8; ++j) acc[j] += bf2f((u16)r0[j]);
        if (VA == 16) {
            bf8 r1 = *(const bf8*)(row + 8);
#pragma unroll
            for (int j = 0; j < 8; ++j) acc[8 + j] += bf2f((u16)r1[j]);
        }
    }
#pragma unroll
    for (int j = 0; j < VA; ++j) {
        acc[j] += __shfl_xor(acc[j], 16);
        acc[j] += __shfl_xor(acc[j], 32);
    }
    if (sub == 0) {
        float inv = dinv[node];
        u16 outv[VA];
#pragma unroll
        for (int j = 0; j < VA; ++j) outv[j] = f2bf(acc[j] * inv);
        u16* o = mean + (size_t)node * D + lr * VA;
        *(bf8*)o = *(bf8*)&outv[0];
        if (VA == 16) *(bf8*)(o + 8) = *(bf8*)&outv[8];
    }
}

// ---------------- bf16 MFMA GEMM, strip-per-wave ----------------
// 512 threads = 8 waves; wave w owns rows [((bx*8+w)*16, +16); computes ALL NC cols.
// A-frags read directly from global (each A row read exactly once).
// W (pre-transposed [NC][K] bf16) staged in LDS once per pass; acc carries both passes.
enum { ACT_NONE = 0, ACT_SIN = 1, ACT_RELU = 2, ACT_SIGMOID1000 = 3, ACT_VAE = 4 };

template <int K, int NC, int ACT, bool OUT_F32, bool TWO_PASS>
__global__ __launch_bounds__(512) void k_gemm(
    const u16* __restrict__ A1, const u16* __restrict__ Wt1,
    const u16* __restrict__ A2, const u16* __restrict__ Wt2,
    const float* __restrict__ bias, void* __restrict__ Cout,
    float* __restrict__ out_mean, float* __restrict__ out_lv,
    const float* __restrict__ eps) {
    constexpr int PK = K + 8;   // padded LDS row stride (elements)
    constexpr int M = N_NODES;
    constexpr int CH = K / 8;   // 16B chunks per W row
    extern __shared__ char smem[];
    u16* Bs = (u16*)smem;

    const int t = threadIdx.x;
    const int lane = t & 63;
    const int wave = t >> 6;
    const int lr = lane & 15;
    const int sub = lane >> 4;
    const int row0 = (blockIdx.x * 8 + wave) * 16;
    const int arow = row0 + lr;
    const bool rowOK = arow < M;

    f32x4 acc[NC / 16];
#pragma unroll
    for (int i = 0; i < NC / 16; ++i) acc[i] = (f32x4){0.f, 0.f, 0.f, 0.f};

    auto stage = [&](const u16* __restrict__ Wt) {
#pragma unroll
        for (int i = 0; i < NC * CH / 512; ++i) {
            int c = t + i * 512;
            int r = c / CH, kc = c % CH;
            *(bf8*)&Bs[r * PK + kc * 8] =
                *(const bf8*)(Wt + (size_t)r * K + kc * 8);
        }
    };

    auto kloop = [&](const u16* __restrict__ A) {
        const u16* ap = A + (size_t)arow * K + sub * 8;
#pragma unroll
        for (int ks = 0; ks < K / 32; ++ks) {
            bf8 a = {0, 0, 0, 0, 0, 0, 0, 0};
            if (rowOK) a = *(const bf8*)(ap + ks * 32);
#pragma unroll
            for (int ni = 0; ni < NC / 16; ++ni) {
                bf8 b = *(const bf8*)&Bs[(ni * 16 + lr) * PK + ks * 32 + sub * 8];
                acc[ni] =
                    __builtin_amdgcn_mfma_f32_16x16x32_bf16(a, b, acc[ni], 0, 0, 0);
            }
        }
    };

    stage(Wt1);
    __syncthreads();
    kloop(A1);
    if (TWO_PASS) {
        __syncthreads();
        stage(Wt2);
        __syncthreads();
        kloop(A2);
    }

    if (ACT == ACT_VAE) {
        // NC == 256: cols 0-127 = mean, 128-255 = log_var; same lane holds both.
#pragma unroll
        for (int ni = 0; ni < 8; ++ni) {
            int col = ni * 16 + lr;
            float bm = bias[col];
            float bl = bias[col + 128];
#pragma unroll
            for (int r = 0; r < 4; ++r) {
                int row = row0 + sub * 4 + r;
                if (row >= M) continue;
                float mv = acc[ni][r] + bm;
                float lv = acc[ni + 8][r] + bl;
                size_t o = (size_t)row * 128 + col;
                out_mean[o] = mv;
                out_lv[o] = lv;
                ((u16*)Cout)[o] = f2bf(mv + __expf(lv) * eps[o]);
            }
        }
    } else {
#pragma unroll
        for (int ni = 0; ni < NC / 16; ++ni) {
            int col = ni * 16 + lr;
            float bv = bias[col];
#pragma unroll
            for (int r = 0; r < 4; ++r) {
                int row = row0 + sub * 4 + r;
                if (row >= M) continue;
                float v = acc[ni][r] + bv;
                if (ACT == ACT_SIN) v = __sinf(v);
                else if (ACT == ACT_RELU) v = fmaxf(v, 0.f);
                else if (ACT == ACT_SIGMOID1000) v = 1000.f / (1.f + __expf(-v));
                if (OUT_F32)
                    ((float*)Cout)[(size_t)row * NC + col] = v;
                else
                    ((u16*)Cout)[(size_t)row * NC + col] = f2bf(v);
            }
        }
    }
}

extern "C" void kernel_launch(void* const* d_in, const int* in_sizes, int n_in,
                              void* d_out, int out_size, void* d_ws,
                              size_t ws_size, hipStream_t stream) {
    const int N = N_NODES;
    const float* x = (const float*)d_in[0];
    const int* ei = (const int*)d_in[1];
    const float* eps = (const float*)d_in[2];
    const float* Wl1 = (const float*)d_in[3];
    const float* bl1 = (const float*)d_in[4];
    const float* Wr1 = (const float*)d_in[5];
    const float* Wl2 = (const float*)d_in[6];
    const float* bl2 = (const float*)d_in[7];
    const float* Wr2 = (const float*)d_in[8];
    const float* Wl3 = (const float*)d_in[9];
    const float* bl3 = (const float*)d_in[10];
    const float* Wr3 = (const float*)d_in[11];
    const float* Wl4 = (const float*)d_in[12];
    const float* bl4 = (const float*)d_in[13];
    const float* Wr4 = (const float*)d_in[14];
    const float* W_lin = (const float*)d_in[15];
    const float* b_lin = (const float*)d_in[16];

    const int* src = ei;
    const int* dst = ei + E_EDGES;

    char* w = (char*)d_ws;
    auto alloc = [&](size_t b) {
        void* p = (void*)w;
        w += (b + 255) & ~(size_t)255;
        return p;
    };
    int* deg = (int*)alloc((size_t)N * 4);
    int* rowptr = (int*)alloc((size_t)(N + 1) * 4);
    int* cursor = (int*)alloc((size_t)N * 4);
    int* colidx = (int*)alloc((size_t)E_EDGES * 4);
    float* dinv = (float*)alloc((size_t)N * 4);
    int* bsum = (int*)alloc(64 * 4);
    int* bofs = (int*)alloc(64 * 4);
    u16* hbA = (u16*)alloc((size_t)N * 256 * 2);
    u16* hbB = (u16*)alloc((size_t)N * 256 * 2);
    u16* hbC = (u16*)alloc((size_t)N * 256 * 2);
    static const int wK[9] = {128, 128, 256, 256, 128, 128, 128, 128, 128};
    static const int wN[9] = {256, 256, 256, 256, 128, 128, 128, 128, 64};
    u16* Wt[9];
    for (int i = 0; i < 9; ++i) Wt[i] = (u16*)alloc((size_t)wK[i] * wN[i] * 2);

    float* out_final = (float*)d_out;              // N x 64
    float* out_mean = out_final + (size_t)N * 64;  // N x 128
    float* out_lv = out_mean + (size_t)N * 128;    // N x 128

    hipMemsetAsync(deg, 0, (size_t)N * 4, stream);
    hipMemsetAsync(cursor, 0, (size_t)N * 4, stream);

    WtArgs wa;
    const float* wsrc[9] = {Wl1, Wr1, Wl2, Wr2, Wl3, Wr3, Wl4, Wr4, W_lin};
    for (int i = 0; i < 9; ++i) {
        wa.src[i] = wsrc[i];
        wa.dst[i] = Wt[i];
        wa.K[i] = wK[i];
        wa.N[i] = wN[i];
    }
    k_wt<<<dim3(64, 9), 256, 0, stream>>>(wa);

    k_prep<<<2048, 256, 0, stream>>>(x, hbA);
    k_count<<<3125, 256, 0, stream>>>(dst, deg);
    k_scan1<<<SCAN_B, 1024, 0, stream>>>(deg, bsum);
    k_scan2<<<1, 64, 0, stream>>>(bsum, bofs);
    k_scan3<<<SCAN_B, 1024, 0, stream>>>(deg, bofs, rowptr, dinv);
    k_fill<<<3125, 256, 0, stream>>>(src, dst, rowptr, cursor, colidx);

    const int aggBlocks = (N * 64 + 255) / 256;    // one wave per node
    const int gx = (N / 16 + 7) / 8;               // 391 blocks of 8 wave-strips
    auto shm = [](int K, int NC) { return (size_t)NC * (K + 8) * 2; };

    // conv1: h1 = sin(mean(h0)@Wl1 + bl1 + h0@Wr1)  (N x 256) -> hbC
    k_aggregate<128><<<aggBlocks, 256, 0, stream>>>(hbA, rowptr, colidx, dinv,
                                                    hbB);
    k_gemm<128, 256, ACT_SIN, false, true><<<gx, 512, shm(128, 256), stream>>>(
        hbB, Wt[0], hbA, Wt[1], bl1, hbC, nullptr, nullptr, nullptr);

    // conv2 + fused reparam: writes out_mean, out_lv, z(bf16)->hbA
    k_aggregate<256><<<aggBlocks, 256, 0, stream>>>(hbC, rowptr, colidx, dinv,
                                                    hbB);
    k_gemm<256, 256, ACT_VAE, false, true><<<gx, 512, shm(256, 256), stream>>>(
        hbB, Wt[2], hbC, Wt[3], bl2, hbA, out_mean, out_lv, eps);

    // conv3: h3 = relu(mean(z)@Wl3 + bl3 + z@Wr3)   (N x 128) -> hbC
    k_aggregate<128><<<aggBlocks, 256, 0, stream>>>(hbA, rowptr, colidx, dinv,
                                                    hbB);
    k_gemm<128, 128, ACT_RELU, false, true><<<gx, 512, shm(128, 128), stream>>>(
        hbB, Wt[4], hbA, Wt[5], bl3, hbC, nullptr, nullptr, nullptr);

    // conv4: h4 = relu(mean(h3)@Wl4 + bl4 + h3@Wr4) (N x 128) -> hbA
    k_aggregate<128><<<aggBlocks, 256, 0, stream>>>(hbC, rowptr, colidx, dinv,
                                                    hbB);
    k_gemm<128, 128, ACT_RELU, false, true><<<gx, 512, shm(128, 128), stream>>>(
        hbB, Wt[6], hbC, Wt[7], bl4, hbA, nullptr, nullptr, nullptr);

    // out = sigmoid(h4 @ W_lin + b_lin) * 1000      (N x 64, fp32) -> d_out
    k_gemm<128, 64, ACT_SIGMOID1000, true, false>
        <<<gx, 512, shm(128, 64), stream>>>(hbA, Wt[8], nullptr, nullptr, b_lin,
                                            out_final, nullptr, nullptr, nullptr);
}

// Round 5
// 380.616 us; speedup vs baseline: 2.8031x; 1.0261x over previous
//
#include <hip/hip_runtime.h>
#include <hip/hip_bf16.h>

#define N_NODES 50000
#define E_EDGES 800000

using u16 = unsigned short;
typedef short bf8 __attribute__((ext_vector_type(8)));
typedef float f32x4 __attribute__((ext_vector_type(4)));

__device__ __forceinline__ float bf2f(u16 h) {
    union { unsigned u; float f; } v;
    v.u = ((unsigned)h) << 16;
    return v.f;
}
__device__ __forceinline__ u16 f2bf(float f) {
    union { float f; unsigned u; } v;
    v.f = f;
    unsigned r = v.u + 0x7FFF + ((v.u >> 16) & 1);
    return (u16)(r >> 16);
}

// ---------------- weight transpose+cast: Wt[n][k] = bf16(W[k][n]) ----------------
struct WtArgs {
    const float* src[9];
    u16* dst[9];
    int K[9];
    int N[9];
};

__global__ __launch_bounds__(256) void k_wt(WtArgs a) {
    int wi = blockIdx.y;
    int K = a.K[wi], Nn = a.N[wi];
    int tot = K * Nn;
    for (int i = blockIdx.x * 256 + threadIdx.x; i < tot; i += gridDim.x * 256) {
        int n = i / K, k = i % K;
        a.dst[wi][i] = f2bf(a.src[wi][(size_t)k * Nn + n]);
    }
}

// ---------------- prep: h0 = x/1000 - 0.5, fp32 -> bf16 ----------------
__global__ __launch_bounds__(256) void k_prep(const float* __restrict__ x,
                                              u16* __restrict__ h0) {
    int total = N_NODES * 128 / 4;
    for (int i = blockIdx.x * 256 + threadIdx.x; i < total;
         i += gridDim.x * 256) {
        float4 v = *(const float4*)(x + (size_t)i * 4);
        ushort4 o;
        o.x = f2bf(v.x * 0.001f - 0.5f);
        o.y = f2bf(v.y * 0.001f - 0.5f);
        o.z = f2bf(v.z * 0.001f - 0.5f);
        o.w = f2bf(v.w * 0.001f - 0.5f);
        *(ushort4*)(h0 + (size_t)i * 4) = o;
    }
}

// ---------------- degree count ----------------
__global__ void k_count(const int* __restrict__ dst, int* __restrict__ deg) {
    for (int i = blockIdx.x * blockDim.x + threadIdx.x; i < E_EDGES;
         i += gridDim.x * blockDim.x)
        atomicAdd(&deg[dst[i]], 1);
}

// ---------------- 3-phase parallel exclusive scan ----------------
#define SCAN_B 49  // ceil(50000/1024)

__global__ __launch_bounds__(1024) void k_scan1(const int* __restrict__ deg,
                                                int* __restrict__ bsum) {
    __shared__ int sm[1024];
    int i = blockIdx.x * 1024 + threadIdx.x;
    sm[threadIdx.x] = (i < N_NODES) ? deg[i] : 0;
    __syncthreads();
    for (int ofs = 512; ofs > 0; ofs >>= 1) {
        if (threadIdx.x < ofs) sm[threadIdx.x] += sm[threadIdx.x + ofs];
        __syncthreads();
    }
    if (threadIdx.x == 0) bsum[blockIdx.x] = sm[0];
}

__global__ void k_scan2(const int* __restrict__ bsum, int* __restrict__ bofs) {
    int l = threadIdx.x;  // one wave of 64
    int v = (l < SCAN_B) ? bsum[l] : 0;
    int orig = v;
    for (int d = 1; d < 64; d <<= 1) {
        int u = __shfl_up(v, d, 64);
        if (l >= d) v += u;
    }
    if (l < SCAN_B) bofs[l] = v - orig;  // exclusive
}

__global__ __launch_bounds__(1024) void k_scan3(const int* __restrict__ deg,
                                                const int* __restrict__ bofs,
                                                int* __restrict__ rowptr,
                                                float* __restrict__ dinv) {
    __shared__ int sm[1024];
    int i = blockIdx.x * 1024 + threadIdx.x;
    int d = (i < N_NODES) ? deg[i] : 0;
    sm[threadIdx.x] = d;
    __syncthreads();
    for (int ofs = 1; ofs < 1024; ofs <<= 1) {
        int u = (threadIdx.x >= (unsigned)ofs) ? sm[threadIdx.x - ofs] : 0;
        __syncthreads();
        sm[threadIdx.x] += u;
        __syncthreads();
    }
    if (i < N_NODES) {
        int incl = sm[threadIdx.x] + bofs[blockIdx.x];
        rowptr[i] = incl - d;
        dinv[i] = 1.0f / fmaxf((float)d, 1.0f);
        if (i == N_NODES - 1) rowptr[N_NODES] = incl;
    }
}

// ---------------- CSR fill ----------------
__global__ void k_fill(const int* __restrict__ src, const int* __restrict__ dst,
                       const int* __restrict__ rowptr, int* __restrict__ cursor,
                       int* __restrict__ colidx) {
    for (int i = blockIdx.x * blockDim.x + threadIdx.x; i < E_EDGES;
         i += gridDim.x * blockDim.x) {
        int d = dst[i];
        int pos = rowptr[d] + atomicAdd(&cursor[d], 1);
        colidx[pos] = src[i];
    }
}

// ---------------- neighbor-mean aggregation: 1 wave/node, 16 lanes/edge ----------------
template <int D>
__global__ __launch_bounds__(256) void k_aggregate(
    const u16* __restrict__ h, const int* __restrict__ rowptr,
    const int* __restrict__ colidx, const float* __restrict__ dinv,
    u16* __restrict__ mean) {
    constexpr int VA = D / 16;  // bf16 per lane (8 or 16)
    int node = (int)((blockIdx.x * 256 + threadIdx.x) >> 6);
    int lane = threadIdx.x & 63;
    if (node >= N_NODES) return;
    int sub = lane >> 4, lr = lane & 15;
    int beg = rowptr[node], end = rowptr[node + 1];
    float acc[VA] = {};
    for (int e = beg + sub; e < end; e += 4) {
        int s = colidx[e];
        const u16* row = h + (size_t)s * D + lr * VA;
        bf8 r0 = *(const bf8*)row;
#pragma unroll
        for (int j = 0; j < 8; ++j) acc[j] += bf2f((u16)r0[j]);
        if (VA == 16) {
            bf8 r1 = *(const bf8*)(row + 8);
#pragma unroll
            for (int j = 0; j < 8; ++j) acc[8 + j] += bf2f((u16)r1[j]);
        }
    }
#pragma unroll
    for (int j = 0; j < VA; ++j) {
        acc[j] += __shfl_xor(acc[j], 16);
        acc[j] += __shfl_xor(acc[j], 32);
    }
    if (sub == 0) {
        float inv = dinv[node];
        u16 outv[VA];
#pragma unroll
        for (int j = 0; j < VA; ++j) outv[j] = f2bf(acc[j] * inv);
        u16* o = mean + (size_t)node * D + lr * VA;
        *(bf8*)o = *(bf8*)&outv[0];
        if (VA == 16) *(bf8*)(o + 8) = *(bf8*)&outv[8];
    }
}

// ---------------- bf16 MFMA GEMM, strip-per-wave, K-chunked W staging ----------------
// 512 threads = 8 waves; wave w owns rows [(bx*8+w)*16, +16); computes ALL NC cols.
// A-frags read directly from global (each A row read exactly once), prefetched
// into regs before the barrier. W staged in LDS in 64-wide K-chunks (<=37 KB)
// so occupancy is VGPR-capped (~16 waves/CU), not LDS-capped.
enum { ACT_NONE = 0, ACT_SIN = 1, ACT_RELU = 2, ACT_SIGMOID1000 = 3, ACT_VAE = 4 };

template <int K, int NC, int ACT, bool OUT_F32, bool TWO_PASS>
__global__ __launch_bounds__(512, 4) void k_gemm(
    const u16* __restrict__ A1, const u16* __restrict__ Wt1,
    const u16* __restrict__ A2, const u16* __restrict__ Wt2,
    const float* __restrict__ bias, void* __restrict__ Cout,
    float* __restrict__ out_mean, float* __restrict__ out_lv,
    const float* __restrict__ eps) {
    constexpr int BK = 64;       // K-chunk
    constexpr int PBK = BK + 8;  // padded LDS row stride (elements)
    constexpr int M = N_NODES;
    extern __shared__ char smem[];
    u16* Bs = (u16*)smem;  // [NC][PBK]

    const int t = threadIdx.x;
    const int lane = t & 63;
    const int wave = t >> 6;
    const int lr = lane & 15;
    const int sub = lane >> 4;
    const int row0 = (blockIdx.x * 8 + wave) * 16;
    const int arow = row0 + lr;
    const bool rowOK = arow < M;

    f32x4 acc[NC / 16];
#pragma unroll
    for (int i = 0; i < NC / 16; ++i) acc[i] = (f32x4){0.f, 0.f, 0.f, 0.f};

    // one pass over A@Wt, chunked by BK in K
    auto pass = [&](const u16* __restrict__ A, const u16* __restrict__ Wt) {
        const u16* ap = A + (size_t)arow * K + sub * 8;
#pragma unroll
        for (int c0 = 0; c0 < K; c0 += BK) {
            // stage W[:, c0:c0+64] -> LDS  (NC*8 bf8-chunks spread over 512 thr)
#pragma unroll
            for (int i = 0; i < NC * (BK / 8) / 512; ++i) {
                int c = t + i * 512;
                int r = c >> 3, kc = c & 7;
                *(bf8*)&Bs[r * PBK + kc * 8] =
                    *(const bf8*)(Wt + (size_t)r * K + c0 + kc * 8);
            }
            // prefetch this chunk's A fragments (overlaps the barrier)
            bf8 a0 = {0, 0, 0, 0, 0, 0, 0, 0}, a1 = a0;
            if (rowOK) {
                a0 = *(const bf8*)(ap + c0);
                a1 = *(const bf8*)(ap + c0 + 32);
            }
            __syncthreads();
#pragma unroll
            for (int ni = 0; ni < NC / 16; ++ni) {
                bf8 b = *(const bf8*)&Bs[(ni * 16 + lr) * PBK + sub * 8];
                acc[ni] =
                    __builtin_amdgcn_mfma_f32_16x16x32_bf16(a0, b, acc[ni], 0, 0, 0);
            }
#pragma unroll
            for (int ni = 0; ni < NC / 16; ++ni) {
                bf8 b = *(const bf8*)&Bs[(ni * 16 + lr) * PBK + 32 + sub * 8];
                acc[ni] =
                    __builtin_amdgcn_mfma_f32_16x16x32_bf16(a1, b, acc[ni], 0, 0, 0);
            }
            __syncthreads();
        }
    };

    pass(A1, Wt1);
    if (TWO_PASS) pass(A2, Wt2);

    if (ACT == ACT_VAE) {
        // NC == 256: cols 0-127 = mean, 128-255 = log_var; same lane holds both.
#pragma unroll
        for (int ni = 0; ni < 8; ++ni) {
            int col = ni * 16 + lr;
            float bm = bias[col];
            float bl = bias[col + 128];
#pragma unroll
            for (int r = 0; r < 4; ++r) {
                int row = row0 + sub * 4 + r;
                if (row >= M) continue;
                float mv = acc[ni][r] + bm;
                float lv = acc[ni + 8][r] + bl;
                size_t o = (size_t)row * 128 + col;
                out_mean[o] = mv;
                out_lv[o] = lv;
                ((u16*)Cout)[o] = f2bf(mv + __expf(lv) * eps[o]);
            }
        }
    } else {
#pragma unroll
        for (int ni = 0; ni < NC / 16; ++ni) {
            int col = ni * 16 + lr;
            float bv = bias[col];
#pragma unroll
            for (int r = 0; r < 4; ++r) {
                int row = row0 + sub * 4 + r;
                if (row >= M) continue;
                float v = acc[ni][r] + bv;
                if (ACT == ACT_SIN) v = __sinf(v);
                else if (ACT == ACT_RELU) v = fmaxf(v, 0.f);
                else if (ACT == ACT_SIGMOID1000) v = 1000.f / (1.f + __expf(-v));
                if (OUT_F32)
                    ((float*)Cout)[(size_t)row * NC + col] = v;
                else
                    ((u16*)Cout)[(size_t)row * NC + col] = f2bf(v);
            }
        }
    }
}

extern "C" void kernel_launch(void* const* d_in, const int* in_sizes, int n_in,
                              void* d_out, int out_size, void* d_ws,
                              size_t ws_size, hipStream_t stream) {
    const int N = N_NODES;
    const float* x = (const float*)d_in[0];
    const int* ei = (const int*)d_in[1];
    const float* eps = (const float*)d_in[2];
    const float* Wl1 = (const float*)d_in[3];
    const float* bl1 = (const float*)d_in[4];
    const float* Wr1 = (const float*)d_in[5];
    const float* Wl2 = (const float*)d_in[6];
    const float* bl2 = (const float*)d_in[7];
    const float* Wr2 = (const float*)d_in[8];
    const float* Wl3 = (const float*)d_in[9];
    const float* bl3 = (const float*)d_in[10];
    const float* Wr3 = (const float*)d_in[11];
    const float* Wl4 = (const float*)d_in[12];
    const float* bl4 = (const float*)d_in[13];
    const float* Wr4 = (const float*)d_in[14];
    const float* W_lin = (const float*)d_in[15];
    const float* b_lin = (const float*)d_in[16];

    const int* src = ei;
    const int* dst = ei + E_EDGES;

    char* w = (char*)d_ws;
    auto alloc = [&](size_t b) {
        void* p = (void*)w;
        w += (b + 255) & ~(size_t)255;
        return p;
    };
    int* deg = (int*)alloc((size_t)N * 4);
    int* rowptr = (int*)alloc((size_t)(N + 1) * 4);
    int* cursor = (int*)alloc((size_t)N * 4);
    int* colidx = (int*)alloc((size_t)E_EDGES * 4);
    float* dinv = (float*)alloc((size_t)N * 4);
    int* bsum = (int*)alloc(64 * 4);
    int* bofs = (int*)alloc(64 * 4);
    u16* hbA = (u16*)alloc((size_t)N * 256 * 2);
    u16* hbB = (u16*)alloc((size_t)N * 256 * 2);
    u16* hbC = (u16*)alloc((size_t)N * 256 * 2);
    static const int wK[9] = {128, 128, 256, 256, 128, 128, 128, 128, 128};
    static const int wN[9] = {256, 256, 256, 256, 128, 128, 128, 128, 64};
    u16* Wt[9];
    for (int i = 0; i < 9; ++i) Wt[i] = (u16*)alloc((size_t)wK[i] * wN[i] * 2);

    float* out_final = (float*)d_out;              // N x 64
    float* out_mean = out_final + (size_t)N * 64;  // N x 128
    float* out_lv = out_mean + (size_t)N * 128;    // N x 128

    hipMemsetAsync(deg, 0, (size_t)N * 4, stream);
    hipMemsetAsync(cursor, 0, (size_t)N * 4, stream);

    WtArgs wa;
    const float* wsrc[9] = {Wl1, Wr1, Wl2, Wr2, Wl3, Wr3, Wl4, Wr4, W_lin};
    for (int i = 0; i < 9; ++i) {
        wa.src[i] = wsrc[i];
        wa.dst[i] = Wt[i];
        wa.K[i] = wK[i];
        wa.N[i] = wN[i];
    }
    k_wt<<<dim3(64, 9), 256, 0, stream>>>(wa);

    k_prep<<<2048, 256, 0, stream>>>(x, hbA);
    k_count<<<3125, 256, 0, stream>>>(dst, deg);
    k_scan1<<<SCAN_B, 1024, 0, stream>>>(deg, bsum);
    k_scan2<<<1, 64, 0, stream>>>(bsum, bofs);
    k_scan3<<<SCAN_B, 1024, 0, stream>>>(deg, bofs, rowptr, dinv);
    k_fill<<<3125, 256, 0, stream>>>(src, dst, rowptr, cursor, colidx);

    const int aggBlocks = (N * 64 + 255) / 256;    // one wave per node
    const int gx = (N / 16 + 7) / 8;               // 391 blocks of 8 wave-strips
    auto shm = [](int NC) { return (size_t)NC * 72 * 2; };  // [NC][64+8] bf16

    // conv1: h1 = sin(mean(h0)@Wl1 + bl1 + h0@Wr1)  (N x 256) -> hbC
    k_aggregate<128><<<aggBlocks, 256, 0, stream>>>(hbA, rowptr, colidx, dinv,
                                                    hbB);
    k_gemm<128, 256, ACT_SIN, false, true><<<gx, 512, shm(256), stream>>>(
        hbB, Wt[0], hbA, Wt[1], bl1, hbC, nullptr, nullptr, nullptr);

    // conv2 + fused reparam: writes out_mean, out_lv, z(bf16)->hbA
    k_aggregate<256><<<aggBlocks, 256, 0, stream>>>(hbC, rowptr, colidx, dinv,
                                                    hbB);
    k_gemm<256, 256, ACT_VAE, false, true><<<gx, 512, shm(256), stream>>>(
        hbB, Wt[2], hbC, Wt[3], bl2, hbA, out_mean, out_lv, eps);

    // conv3: h3 = relu(mean(z)@Wl3 + bl3 + z@Wr3)   (N x 128) -> hbC
    k_aggregate<128><<<aggBlocks, 256, 0, stream>>>(hbA, rowptr, colidx, dinv,
                                                    hbB);
    k_gemm<128, 128, ACT_RELU, false, true><<<gx, 512, shm(128), stream>>>(
        hbB, Wt[4], hbA, Wt[5], bl3, hbC, nullptr, nullptr, nullptr);

    // conv4: h4 = relu(mean(h3)@Wl4 + bl4 + h3@Wr4) (N x 128) -> hbA
    k_aggregate<128><<<aggBlocks, 256, 0, stream>>>(hbC, rowptr, colidx, dinv,
                                                    hbB);
    k_gemm<128, 128, ACT_RELU, false, true><<<gx, 512, shm(128), stream>>>(
        hbB, Wt[6], hbC, Wt[7], bl4, hbA, nullptr, nullptr, nullptr);

    // out = sigmoid(h4 @ W_lin + b_lin) * 1000      (N x 64, fp32) -> d_out
    k_gemm<128, 64, ACT_SIGMOID1000, true, false>
        <<<gx, 512, shm(64), stream>>>(hbA, Wt[8], nullptr, nullptr, b_lin,
                                       out_final, nullptr, nullptr, nullptr);
}